// Round 8
// baseline (360.784 us; speedup 1.0000x reference)
//
#include <hip/hip_runtime.h>

// Transformer-XL RelPartialLearnableMultiHeadAttn forward, MI355X gfx950.
// Pipeline: f32->bf16 converts, G1 qkv GEMM (epilogue->Q+biases/K/V),
// G2 r_head_k GEMM, flash attention with rel-shift band-BD via MFMA,
// G3 output GEMM, residual+LayerNorm.

typedef __attribute__((ext_vector_type(8))) short short8;
typedef __attribute__((ext_vector_type(4))) float f32x4;

#define AS1C(p) ((const __attribute__((address_space(1))) void*)(p))
#define AS3(p)  ((__attribute__((address_space(3))) void*)(p))

__device__ __forceinline__ f32x4 mfma16(short8 a, short8 b, f32x4 c) {
  return __builtin_amdgcn_mfma_f32_16x16x32_bf16(a, b, c, 0, 0, 0);
}

__device__ __forceinline__ unsigned short f2bf(float x) {
  union { float f; unsigned int u; } v; v.f = x;
  unsigned int r = v.u + 0x7fffu + ((v.u >> 16) & 1u);
  return (unsigned short)(r >> 16);
}
__device__ __forceinline__ float bf2f(unsigned short x) {
  union { unsigned int u; float f; } v; v.u = ((unsigned int)x) << 16;
  return v.f;
}
__device__ __forceinline__ f32x4 f4zero() {
  f32x4 z = {0.f, 0.f, 0.f, 0.f};
  return z;
}

// ---------------- f32 -> bf16 convert ----------------
__global__ __launch_bounds__(256) void k_conv(const float* __restrict__ src,
                                              unsigned short* __restrict__ dst) {
  size_t i = ((size_t)blockIdx.x * 256 + threadIdx.x) * 4;
  float4 v = *(const float4*)(src + i);
  unsigned int lo = (unsigned int)f2bf(v.x) | ((unsigned int)f2bf(v.y) << 16);
  unsigned int hi = (unsigned int)f2bf(v.z) | ((unsigned int)f2bf(v.w) << 16);
  uint2 o; o.x = lo; o.y = hi;
  *(uint2*)(dst + i) = o;
}

// ---------------- shared GEMM core: C[128][128] = A[M][1024] @ B[N][1024]^T ----------------
// block 256 threads, 4 waves in 2x2, each wave 64x64 (4x4 fragments of 16x16x32 bf16 MFMA)
__device__ __forceinline__ void gemm_core(const unsigned short* __restrict__ A,
                                          const unsigned short* __restrict__ B,
                                          int m0, int n0,
                                          unsigned short* As, unsigned short* Bs,
                                          f32x4 (&acc)[4][4]) {
  const int tid = threadIdx.x;
  const int lane = tid & 63;
  const int w = tid >> 6;
  const int wm = (w >> 1) * 64, wn = (w & 1) * 64;
  const int l15 = lane & 15, lg = lane >> 4;
#pragma unroll
  for (int mi = 0; mi < 4; ++mi)
#pragma unroll
    for (int ni = 0; ni < 4; ++ni) acc[mi][ni] = f4zero();

  const int o = tid * 16;            // byte offset within 8KB tile
  const int row0 = o >> 6;           // 64B per row (32 bf16)
  const int col0 = (o >> 1) & 31;    // element col
  const int ldst = o >> 1;           // element offset in LDS

  for (int kt = 0; kt < 1024; kt += 32) {
    __syncthreads();
#pragma unroll
    for (int u = 0; u < 2; ++u) {
      __builtin_amdgcn_global_load_lds(
          AS1C(A + (size_t)(m0 + row0 + u * 64) * 1024 + kt + col0),
          AS3(As + ldst + u * 2048), 16, 0, 0);
      __builtin_amdgcn_global_load_lds(
          AS1C(B + (size_t)(n0 + row0 + u * 64) * 1024 + kt + col0),
          AS3(Bs + ldst + u * 2048), 16, 0, 0);
    }
    __syncthreads();
    short8 af[4], bfv[4];
#pragma unroll
    for (int mi = 0; mi < 4; ++mi)
      af[mi] = *(const short8*)&As[(wm + mi * 16 + l15) * 32 + lg * 8];
#pragma unroll
    for (int ni = 0; ni < 4; ++ni)
      bfv[ni] = *(const short8*)&Bs[(wn + ni * 16 + l15) * 32 + lg * 8];
#pragma unroll
    for (int mi = 0; mi < 4; ++mi)
#pragma unroll
      for (int ni = 0; ni < 4; ++ni)
        acc[mi][ni] = mfma16(af[mi], bfv[ni], acc[mi][ni]);
  }
}

// ---------------- G1: qkv = A_cat @ Wqkv^T, scatter epilogue ----------------
__global__ __launch_bounds__(256) void k_gemm_qkv(
    const unsigned short* __restrict__ A, const unsigned short* __restrict__ B,
    unsigned short* __restrict__ Qrw, unsigned short* __restrict__ Qrr,
    unsigned short* __restrict__ Kd, unsigned short* __restrict__ Vd,
    const float* __restrict__ rwb, const float* __restrict__ rrb) {
  __shared__ unsigned short As[4096], Bs[4096];
  f32x4 acc[4][4];
  const int m0 = blockIdx.y * 128, n0 = blockIdx.x * 128;
  gemm_core(A, B, m0, n0, As, Bs, acc);
  const int tid = threadIdx.x, lane = tid & 63, w = tid >> 6;
  const int wm = (w >> 1) * 64, wn = (w & 1) * 64;
  const int l15 = lane & 15, lg = lane >> 4;
#pragma unroll
  for (int mi = 0; mi < 4; ++mi)
#pragma unroll
    for (int ni = 0; ni < 4; ++ni)
#pragma unroll
      for (int r = 0; r < 4; ++r) {
        float v = acc[mi][ni][r];
        int gm = m0 + wm + mi * 16 + lg * 4 + r;   // row = t*2+b
        int gn = n0 + wn + ni * 16 + l15;          // col in [0,3072)
        int t = gm >> 1, b = gm & 1;
        if (gn < 1024) {
          if (t >= 1024) {  // q keeps only last qlen rows
            int i = t - 1024;
            int hn = gn >> 6, d = gn & 63;
            size_t off = (((size_t)(b * 16 + hn)) * 1024 + i) * 64 + d;
            Qrw[off] = f2bf(v + rwb[gn]);
            Qrr[off] = f2bf(v + rrb[gn]);
          }
        } else if (gn < 2048) {
          int c = gn - 1024, hn = c >> 6, d = c & 63;
          Kd[(((size_t)(b * 16 + hn)) * 2048 + t) * 64 + d] = f2bf(v);
        } else {
          int c = gn - 2048, hn = c >> 6, d = c & 63;
          Vd[(((size_t)(b * 16 + hn)) * 2048 + t) * 64 + d] = f2bf(v);
        }
      }
}

// ---------------- G2: r_head_k = r @ r_W^T -> RK[n][jr][d] ----------------
__global__ __launch_bounds__(256) void k_gemm_rk(
    const unsigned short* __restrict__ A, const unsigned short* __restrict__ B,
    unsigned short* __restrict__ RKd) {
  __shared__ unsigned short As[4096], Bs[4096];
  f32x4 acc[4][4];
  const int m0 = blockIdx.y * 128, n0 = blockIdx.x * 128;
  gemm_core(A, B, m0, n0, As, Bs, acc);
  const int tid = threadIdx.x, lane = tid & 63, w = tid >> 6;
  const int wm = (w >> 1) * 64, wn = (w & 1) * 64;
  const int l15 = lane & 15, lg = lane >> 4;
#pragma unroll
  for (int mi = 0; mi < 4; ++mi)
#pragma unroll
    for (int ni = 0; ni < 4; ++ni)
#pragma unroll
      for (int r = 0; r < 4; ++r) {
        int gm = m0 + wm + mi * 16 + lg * 4 + r;  // jr
        int gn = n0 + wn + ni * 16 + l15;         // n*64+d
        int hn = gn >> 6, d = gn & 63;
        RKd[(((size_t)hn) * 2048 + gm) * 64 + d] = f2bf(acc[mi][ni][r]);
      }
}

// ---------------- G3: attn_out = attn_vec @ o_W^T (f32 out) ----------------
__global__ __launch_bounds__(256) void k_gemm_o(
    const unsigned short* __restrict__ A, const unsigned short* __restrict__ B,
    float* __restrict__ AO) {
  __shared__ unsigned short As[4096], Bs[4096];
  f32x4 acc[4][4];
  const int m0 = blockIdx.y * 128, n0 = blockIdx.x * 128;
  gemm_core(A, B, m0, n0, As, Bs, acc);
  const int tid = threadIdx.x, lane = tid & 63, w = tid >> 6;
  const int wm = (w >> 1) * 64, wn = (w & 1) * 64;
  const int l15 = lane & 15, lg = lane >> 4;
#pragma unroll
  for (int mi = 0; mi < 4; ++mi)
#pragma unroll
    for (int ni = 0; ni < 4; ++ni)
#pragma unroll
      for (int r = 0; r < 4; ++r) {
        int gm = m0 + wm + mi * 16 + lg * 4 + r;
        int gn = n0 + wn + ni * 16 + l15;
        AO[(size_t)gm * 1024 + gn] = acc[mi][ni][r];
      }
}

// ---------------- attention: per (b,n,i-tile64), flash loop over j-tiles64 ----------------
// BD_shifted[i][j] = Qrr[i] . RK[j + 1023 - i]  (verified vs _rel_shift)
__global__ __launch_bounds__(256, 2) void k_attn(
    const unsigned short* __restrict__ Qrw, const unsigned short* __restrict__ Qrr,
    const unsigned short* __restrict__ Kd, const unsigned short* __restrict__ Vd,
    const unsigned short* __restrict__ RKd, unsigned short* __restrict__ AV) {
  __shared__ unsigned short Qrw_s[64][72], Qrr_s[64][72];
  __shared__ unsigned short KP_s[64][72];   // K tile; later aliased by P
  __shared__ unsigned short Vt_s[64][72];   // V transposed [d][j]
  __shared__ unsigned short RK_s[128][72];  // rel-pos band
  __shared__ unsigned short BD_s[64][132];  // band-BD (bf16), cols 0..127

  const int it = blockIdx.x, bn = blockIdx.y;
  const int b = bn >> 4, hn = bn & 15;
  const int i0 = it * 64;
  const int tid = threadIdx.x, lane = tid & 63, w = tid >> 6;
  const int l15 = lane & 15, lg = lane >> 4;
  const int istrip = w * 16;

  {  // load Q tiles (persistent)
    const size_t qbase = (((size_t)(b * 16 + hn)) * 1024 + i0) * 64;
#pragma unroll
    for (int u = 0; u < 2; ++u) {
      int c = tid + u * 256;
      int row = c >> 3, col = (c & 7) * 8;
      *(short8*)&Qrw_s[row][col] = *(const short8*)&Qrw[qbase + row * 64 + col];
      *(short8*)&Qrr_s[row][col] = *(const short8*)&Qrr[qbase + row * 64 + col];
    }
  }

  float m_st[4], l_st[4];
  f32x4 accO[4];
#pragma unroll
  for (int r = 0; r < 4; ++r) { m_st[r] = -1e30f; l_st[r] = 0.f; }
#pragma unroll
  for (int df = 0; df < 4; ++df) accO[df] = f4zero();

  const size_t kvbase = ((size_t)(b * 16 + hn)) * 2048 * 64;
  const int njt = it + 17;

  for (int jt = 0; jt < njt; ++jt) {
    const int j0 = jt * 64;
    __syncthreads();  // prev iter's PV reads done before restage
    // stage K tile + V transposed
#pragma unroll
    for (int u = 0; u < 2; ++u) {
      int c = tid + u * 256;
      int row = c >> 3, col = (c & 7) * 8;
      *(short8*)&KP_s[row][col] = *(const short8*)&Kd[kvbase + (size_t)(j0 + row) * 64 + col];
      short8 vv = *(const short8*)&Vd[kvbase + (size_t)(j0 + row) * 64 + col];
#pragma unroll
      for (int e = 0; e < 8; ++e) Vt_s[col + e][row] = (unsigned short)vv[e];
    }
    // stage RK band: rows jrb .. jrb+127
    const int jrb = j0 + 960 - i0;  // j0 + 1023 - (i0+63)
#pragma unroll
    for (int u = 0; u < 4; ++u) {
      int c = tid + u * 256;
      int row = c >> 3, col = (c & 7) * 8;
      int jr = jrb + row;
      jr = jr < 0 ? 0 : (jr > 2047 ? 2047 : jr);  // clamped rows feed only masked cells
      *(short8*)&RK_s[row][col] = *(const short8*)&RKd[((size_t)hn * 2048 + jr) * 64 + col];
    }
    __syncthreads();  // staging visible

    // AC = Qrw . K^T  (wave strip 16 x 64)
    f32x4 accS[4];
#pragma unroll
    for (int ni = 0; ni < 4; ++ni) accS[ni] = f4zero();
#pragma unroll
    for (int kk = 0; kk < 2; ++kk) {
      short8 aq = *(const short8*)&Qrw_s[istrip + l15][kk * 32 + lg * 8];
#pragma unroll
      for (int ni = 0; ni < 4; ++ni) {
        short8 bk = *(const short8*)&KP_s[ni * 16 + l15][kk * 32 + lg * 8];
        accS[ni] = mfma16(aq, bk, accS[ni]);
      }
    }
    // BD band: strip 16 x 128
    f32x4 accB[8];
#pragma unroll
    for (int fi = 0; fi < 8; ++fi) accB[fi] = f4zero();
#pragma unroll
    for (int kk = 0; kk < 2; ++kk) {
      short8 aq = *(const short8*)&Qrr_s[istrip + l15][kk * 32 + lg * 8];
#pragma unroll
      for (int fi = 0; fi < 8; ++fi) {
        short8 br = *(const short8*)&RK_s[fi * 16 + l15][kk * 32 + lg * 8];
        accB[fi] = mfma16(aq, br, accB[fi]);
      }
    }
#pragma unroll
    for (int fi = 0; fi < 8; ++fi)
#pragma unroll
      for (int r = 0; r < 4; ++r)
        BD_s[istrip + lg * 4 + r][fi * 16 + l15] = f2bf(accB[fi][r]);
    __syncthreads();  // all AC reads of K done -> P may overwrite KP_s

    // S = scale*(AC + BD[tj-ti+63]); mask; online softmax
    float p[4][4], mx[4];
#pragma unroll
    for (int r = 0; r < 4; ++r) mx[r] = -1e30f;
#pragma unroll
    for (int ni = 0; ni < 4; ++ni) {
      const int tj = ni * 16 + l15;
      const int gj = j0 + tj;
#pragma unroll
      for (int r = 0; r < 4; ++r) {
        const int ti = istrip + lg * 4 + r;
        const int gi = i0 + ti;
        float s = accS[ni][r] + bf2f(BD_s[ti][tj - ti + 63]);
        s = (gj <= gi + 1024) ? s * 0.125f : -1e30f;
        p[ni][r] = s;
        mx[r] = fmaxf(mx[r], s);
      }
    }
#pragma unroll
    for (int off = 1; off < 16; off <<= 1)
#pragma unroll
      for (int r = 0; r < 4; ++r) mx[r] = fmaxf(mx[r], __shfl_xor(mx[r], off));
    float rs[4], rowsum[4];
#pragma unroll
    for (int r = 0; r < 4; ++r) {
      float mnew = fmaxf(m_st[r], mx[r]);
      rs[r] = __expf(m_st[r] - mnew);
      m_st[r] = mnew;
      rowsum[r] = 0.f;
    }
#pragma unroll
    for (int ni = 0; ni < 4; ++ni)
#pragma unroll
      for (int r = 0; r < 4; ++r) {
        float e = __expf(p[ni][r] - m_st[r]);
        p[ni][r] = e;
        rowsum[r] += e;
      }
#pragma unroll
    for (int off = 1; off < 16; off <<= 1)
#pragma unroll
      for (int r = 0; r < 4; ++r) rowsum[r] += __shfl_xor(rowsum[r], off);
#pragma unroll
    for (int r = 0; r < 4; ++r) l_st[r] = l_st[r] * rs[r] + rowsum[r];
#pragma unroll
    for (int df = 0; df < 4; ++df) {
      f32x4 t = accO[df];
#pragma unroll
      for (int r = 0; r < 4; ++r) t[r] *= rs[r];
      accO[df] = t;
    }
    // write P (own strip rows; aliases K tile, safe after barrier)
#pragma unroll
    for (int ni = 0; ni < 4; ++ni)
#pragma unroll
      for (int r = 0; r < 4; ++r)
        KP_s[istrip + lg * 4 + r][ni * 16 + l15] = f2bf(p[ni][r]);
    // PV: accO += P @ V
#pragma unroll
    for (int kk = 0; kk < 2; ++kk) {
      short8 ap = *(const short8*)&KP_s[istrip + l15][kk * 32 + lg * 8];
#pragma unroll
      for (int df = 0; df < 4; ++df) {
        short8 bv = *(const short8*)&Vt_s[df * 16 + l15][kk * 32 + lg * 8];
        accO[df] = mfma16(ap, bv, accO[df]);
      }
    }
  }
  // epilogue: attn_vec[(i*2+b)][hn*64+d] = accO / l
#pragma unroll
  for (int df = 0; df < 4; ++df)
#pragma unroll
    for (int r = 0; r < 4; ++r) {
      int ti = istrip + lg * 4 + r;
      int gi = i0 + ti;
      int d = df * 16 + l15;
      float v = accO[df][r] / l_st[r];
      AV[((size_t)gi * 2 + b) * 1024 + hn * 64 + d] = f2bf(v);
    }
}

// ---------------- residual + LayerNorm ----------------
__global__ __launch_bounds__(256) void k_ln(const float* __restrict__ wres,
                                            const float* __restrict__ ao,
                                            const float* __restrict__ g,
                                            const float* __restrict__ bb,
                                            float* __restrict__ out) {
  const int row = blockIdx.x;
  const int t4 = threadIdx.x * 4;
  const float4 xv = *(const float4*)(wres + (size_t)row * 1024 + t4);
  const float4 av = *(const float4*)(ao + (size_t)row * 1024 + t4);
  float x0 = xv.x + av.x, x1 = xv.y + av.y, x2 = xv.z + av.z, x3 = xv.w + av.w;
  float s1 = x0 + x1 + x2 + x3;
  float s2 = x0 * x0 + x1 * x1 + x2 * x2 + x3 * x3;
#pragma unroll
  for (int off = 1; off < 64; off <<= 1) {
    s1 += __shfl_xor(s1, off);
    s2 += __shfl_xor(s2, off);
  }
  __shared__ float red[2][4];
  const int wv = threadIdx.x >> 6;
  if ((threadIdx.x & 63) == 0) { red[0][wv] = s1; red[1][wv] = s2; }
  __syncthreads();
  s1 = red[0][0] + red[0][1] + red[0][2] + red[0][3];
  s2 = red[1][0] + red[1][1] + red[1][2] + red[1][3];
  const float mu = s1 * (1.f / 1024.f);
  const float var = s2 * (1.f / 1024.f) - mu * mu;
  const float inv = rsqrtf(var + 1e-5f);
  const float4 gv = *(const float4*)(g + t4);
  const float4 bv = *(const float4*)(bb + t4);
  float4 ov;
  ov.x = (x0 - mu) * inv * gv.x + bv.x;
  ov.y = (x1 - mu) * inv * gv.y + bv.y;
  ov.z = (x2 - mu) * inv * gv.z + bv.z;
  ov.w = (x3 - mu) * inv * gv.w + bv.w;
  *(float4*)(out + (size_t)row * 1024 + t4) = ov;
}

extern "C" void kernel_launch(void* const* d_in, const int* in_sizes, int n_in,
                              void* d_out, int out_size, void* d_ws, size_t ws_size,
                              hipStream_t stream) {
  const float* w     = (const float*)d_in[0];
  const float* r     = (const float*)d_in[1];
  const float* rwb   = (const float*)d_in[2];
  const float* rrb   = (const float*)d_in[3];
  const float* mems  = (const float*)d_in[4];
  const float* qkv_W = (const float*)d_in[6];
  const float* r_W   = (const float*)d_in[7];
  const float* o_W   = (const float*)d_in[8];
  const float* ln_g  = (const float*)d_in[9];
  const float* ln_b  = (const float*)d_in[10];
  float* out = (float*)d_out;
  char* ws = (char*)d_ws;

  unsigned short* A_cat = (unsigned short*)(ws + 0);          //  8 MB: [4096][1024]
  unsigned short* Wqkv  = (unsigned short*)(ws + 8388608);    //  6 MB: [3072][1024]
  unsigned short* rb    = (unsigned short*)(ws + 14680064);   //  4 MB: [2048][1024]
  unsigned short* Wr    = (unsigned short*)(ws + 18874368);   //  2 MB
  unsigned short* oWb   = (unsigned short*)(ws + 20971520);   //  2 MB
  unsigned short* Qrw   = (unsigned short*)(ws + 23068672);   //  4 MB: [b][n][1024][64]
  unsigned short* Qrr   = (unsigned short*)(ws + 27262976);   //  4 MB
  unsigned short* Kd    = (unsigned short*)(ws + 31457280);   //  8 MB: [b][n][2048][64]
  unsigned short* Vd    = (unsigned short*)(ws + 39845888);   //  8 MB
  unsigned short* RKd   = (unsigned short*)(ws + 48234496);   //  4 MB: [n][2048][64]
  unsigned short* AV    = (unsigned short*)(ws + 52428800);   //  4 MB: [2048][1024]
  float*          AO    = (float*)(ws + 56623104);            //  8 MB: [2048][1024]

  // converts (n/1024 blocks each, 4 elems/thread)
  k_conv<<<2048, 256, 0, stream>>>(mems, A_cat);                  // rows 0..2047
  k_conv<<<2048, 256, 0, stream>>>(w, A_cat + 2048 * 1024);       // rows 2048..4095
  k_conv<<<3072, 256, 0, stream>>>(qkv_W, Wqkv);
  k_conv<<<2048, 256, 0, stream>>>(r, rb);
  k_conv<<<1024, 256, 0, stream>>>(r_W, Wr);
  k_conv<<<1024, 256, 0, stream>>>(o_W, oWb);

  k_gemm_qkv<<<dim3(24, 32), 256, 0, stream>>>(A_cat, Wqkv, Qrw, Qrr, Kd, Vd, rwb, rrb);
  k_gemm_rk<<<dim3(8, 16), 256, 0, stream>>>(rb, Wr, RKd);
  k_attn<<<dim3(16, 32), 256, 0, stream>>>(Qrw, Qrr, Kd, Vd, RKd, AV);
  k_gemm_o<<<dim3(8, 16), 256, 0, stream>>>(AV, oWb, AO);
  k_ln<<<2048, 256, 0, stream>>>(w, AO, ln_g, ln_b, out);
}

// Round 10
// 354.390 us; speedup vs baseline: 1.0180x; 1.0180x over previous
//
#include <hip/hip_runtime.h>

// Transformer-XL RelPartialLearnableMultiHeadAttn forward, MI355X gfx950.
// R9: Vt granule-XOR swizzle (kills 16-way LDS conflicts), Q in registers,
// LDS 72->52.5KB, fused converts.

typedef __attribute__((ext_vector_type(8))) short short8;
typedef __attribute__((ext_vector_type(4))) float f32x4;

#define AS1C(p) ((const __attribute__((address_space(1))) void*)(p))
#define AS3(p)  ((__attribute__((address_space(3))) void*)(p))

__device__ __forceinline__ f32x4 mfma16(short8 a, short8 b, f32x4 c) {
  return __builtin_amdgcn_mfma_f32_16x16x32_bf16(a, b, c, 0, 0, 0);
}

__device__ __forceinline__ unsigned short f2bf(float x) {
  union { float f; unsigned int u; } v; v.f = x;
  unsigned int r = v.u + 0x7fffu + ((v.u >> 16) & 1u);
  return (unsigned short)(r >> 16);
}
__device__ __forceinline__ float bf2f(unsigned short x) {
  union { unsigned int u; float f; } v; v.u = ((unsigned int)x) << 16;
  return v.f;
}
__device__ __forceinline__ f32x4 f4zero() {
  f32x4 z = {0.f, 0.f, 0.f, 0.f};
  return z;
}

// ---------------- fused f32 -> bf16 converts (all 6 regions, one launch) ----------------
__global__ __launch_bounds__(256) void k_conv_all(
    const float* __restrict__ s0, const float* __restrict__ s1,
    const float* __restrict__ s2, const float* __restrict__ s3,
    const float* __restrict__ s4, const float* __restrict__ s5,
    unsigned short* __restrict__ d0, unsigned short* __restrict__ d1,
    unsigned short* __restrict__ d2, unsigned short* __restrict__ d3,
    unsigned short* __restrict__ d4, unsigned short* __restrict__ d5) {
  int b = blockIdx.x;
  const float* src; unsigned short* dst; int off;
  if (b < 2048)       { src = s0; dst = d0; off = b; }
  else if (b < 4096)  { src = s1; dst = d1; off = b - 2048; }
  else if (b < 7168)  { src = s2; dst = d2; off = b - 4096; }
  else if (b < 9216)  { src = s3; dst = d3; off = b - 7168; }
  else if (b < 10240) { src = s4; dst = d4; off = b - 9216; }
  else                { src = s5; dst = d5; off = b - 10240; }
  size_t i = ((size_t)off * 256 + threadIdx.x) * 4;
  float4 v = *(const float4*)(src + i);
  unsigned int lo = (unsigned int)f2bf(v.x) | ((unsigned int)f2bf(v.y) << 16);
  unsigned int hi = (unsigned int)f2bf(v.z) | ((unsigned int)f2bf(v.w) << 16);
  uint2 o; o.x = lo; o.y = hi;
  *(uint2*)(dst + i) = o;
}

// ---------------- shared GEMM core: C[128][128] = A[M][1024] @ B[N][1024]^T ----------------
__device__ __forceinline__ void gemm_core(const unsigned short* __restrict__ A,
                                          const unsigned short* __restrict__ B,
                                          int m0, int n0,
                                          unsigned short* As, unsigned short* Bs,
                                          f32x4 (&acc)[4][4]) {
  const int tid = threadIdx.x;
  const int lane = tid & 63;
  const int w = tid >> 6;
  const int wm = (w >> 1) * 64, wn = (w & 1) * 64;
  const int l15 = lane & 15, lg = lane >> 4;
#pragma unroll
  for (int mi = 0; mi < 4; ++mi)
#pragma unroll
    for (int ni = 0; ni < 4; ++ni) acc[mi][ni] = f4zero();

  const int o = tid * 16;
  const int row0 = o >> 6;
  const int col0 = (o >> 1) & 31;
  const int ldst = o >> 1;

  for (int kt = 0; kt < 1024; kt += 32) {
    __syncthreads();
#pragma unroll
    for (int u = 0; u < 2; ++u) {
      __builtin_amdgcn_global_load_lds(
          AS1C(A + (size_t)(m0 + row0 + u * 64) * 1024 + kt + col0),
          AS3(As + ldst + u * 2048), 16, 0, 0);
      __builtin_amdgcn_global_load_lds(
          AS1C(B + (size_t)(n0 + row0 + u * 64) * 1024 + kt + col0),
          AS3(Bs + ldst + u * 2048), 16, 0, 0);
    }
    __syncthreads();
    short8 af[4], bfv[4];
#pragma unroll
    for (int mi = 0; mi < 4; ++mi)
      af[mi] = *(const short8*)&As[(wm + mi * 16 + l15) * 32 + lg * 8];
#pragma unroll
    for (int ni = 0; ni < 4; ++ni)
      bfv[ni] = *(const short8*)&Bs[(wn + ni * 16 + l15) * 32 + lg * 8];
#pragma unroll
    for (int mi = 0; mi < 4; ++mi)
#pragma unroll
      for (int ni = 0; ni < 4; ++ni)
        acc[mi][ni] = mfma16(af[mi], bfv[ni], acc[mi][ni]);
  }
}

// ---------------- G1: qkv = A_cat @ Wqkv^T, scatter epilogue ----------------
__global__ __launch_bounds__(256) void k_gemm_qkv(
    const unsigned short* __restrict__ A, const unsigned short* __restrict__ B,
    unsigned short* __restrict__ Qrw, unsigned short* __restrict__ Qrr,
    unsigned short* __restrict__ Kd, unsigned short* __restrict__ Vd,
    const float* __restrict__ rwb, const float* __restrict__ rrb) {
  __shared__ unsigned short As[4096], Bs[4096];
  f32x4 acc[4][4];
  const int m0 = blockIdx.y * 128, n0 = blockIdx.x * 128;
  gemm_core(A, B, m0, n0, As, Bs, acc);
  const int tid = threadIdx.x, lane = tid & 63, w = tid >> 6;
  const int wm = (w >> 1) * 64, wn = (w & 1) * 64;
  const int l15 = lane & 15, lg = lane >> 4;
#pragma unroll
  for (int mi = 0; mi < 4; ++mi)
#pragma unroll
    for (int ni = 0; ni < 4; ++ni)
#pragma unroll
      for (int r = 0; r < 4; ++r) {
        float v = acc[mi][ni][r];
        int gm = m0 + wm + mi * 16 + lg * 4 + r;   // row = t*2+b
        int gn = n0 + wn + ni * 16 + l15;          // col in [0,3072)
        int t = gm >> 1, b = gm & 1;
        if (gn < 1024) {
          if (t >= 1024) {
            int i = t - 1024;
            int hn = gn >> 6, d = gn & 63;
            size_t off = (((size_t)(b * 16 + hn)) * 1024 + i) * 64 + d;
            Qrw[off] = f2bf(v + rwb[gn]);
            Qrr[off] = f2bf(v + rrb[gn]);
          }
        } else if (gn < 2048) {
          int c = gn - 1024, hn = c >> 6, d = c & 63;
          Kd[(((size_t)(b * 16 + hn)) * 2048 + t) * 64 + d] = f2bf(v);
        } else {
          int c = gn - 2048, hn = c >> 6, d = c & 63;
          Vd[(((size_t)(b * 16 + hn)) * 2048 + t) * 64 + d] = f2bf(v);
        }
      }
}

// ---------------- G2: r_head_k = r @ r_W^T -> RK[n][jr][d] ----------------
__global__ __launch_bounds__(256) void k_gemm_rk(
    const unsigned short* __restrict__ A, const unsigned short* __restrict__ B,
    unsigned short* __restrict__ RKd) {
  __shared__ unsigned short As[4096], Bs[4096];
  f32x4 acc[4][4];
  const int m0 = blockIdx.y * 128, n0 = blockIdx.x * 128;
  gemm_core(A, B, m0, n0, As, Bs, acc);
  const int tid = threadIdx.x, lane = tid & 63, w = tid >> 6;
  const int wm = (w >> 1) * 64, wn = (w & 1) * 64;
  const int l15 = lane & 15, lg = lane >> 4;
#pragma unroll
  for (int mi = 0; mi < 4; ++mi)
#pragma unroll
    for (int ni = 0; ni < 4; ++ni)
#pragma unroll
      for (int r = 0; r < 4; ++r) {
        int gm = m0 + wm + mi * 16 + lg * 4 + r;
        int gn = n0 + wn + ni * 16 + l15;
        int hn = gn >> 6, d = gn & 63;
        RKd[(((size_t)hn) * 2048 + gm) * 64 + d] = f2bf(acc[mi][ni][r]);
      }
}

// ---------------- G3: attn_out = attn_vec @ o_W^T (f32 out) ----------------
__global__ __launch_bounds__(256) void k_gemm_o(
    const unsigned short* __restrict__ A, const unsigned short* __restrict__ B,
    float* __restrict__ AO) {
  __shared__ unsigned short As[4096], Bs[4096];
  f32x4 acc[4][4];
  const int m0 = blockIdx.y * 128, n0 = blockIdx.x * 128;
  gemm_core(A, B, m0, n0, As, Bs, acc);
  const int tid = threadIdx.x, lane = tid & 63, w = tid >> 6;
  const int wm = (w >> 1) * 64, wn = (w & 1) * 64;
  const int l15 = lane & 15, lg = lane >> 4;
#pragma unroll
  for (int mi = 0; mi < 4; ++mi)
#pragma unroll
    for (int ni = 0; ni < 4; ++ni)
#pragma unroll
      for (int r = 0; r < 4; ++r) {
        int gm = m0 + wm + mi * 16 + lg * 4 + r;
        int gn = n0 + wn + ni * 16 + l15;
        AO[(size_t)gm * 1024 + gn] = acc[mi][ni][r];
      }
}

// ---------------- attention ----------------
// BD_shifted[i][j] = Qrr[i] . RK[j + 1023 - i]
// Vt_s stores V transposed with granule-XOR swizzle: element (d, j) lives at
// column 8*((j>>3) ^ (d>>3)) + (j&7). Write banks = 4*(g^k)+j/2 -> conflict-free.
__global__ __launch_bounds__(256, 3) void k_attn(
    const unsigned short* __restrict__ Qrw, const unsigned short* __restrict__ Qrr,
    const unsigned short* __restrict__ Kd, const unsigned short* __restrict__ Vd,
    const unsigned short* __restrict__ RKd, unsigned short* __restrict__ AV) {
  __shared__ __attribute__((aligned(16))) unsigned short KP_s[64][72];   // K tile; aliased by P
  __shared__ __attribute__((aligned(16))) unsigned short Vt_s[64][64];   // V^T, XOR-swizzled
  __shared__ __attribute__((aligned(16))) unsigned short RK_s[128][72];  // rel-pos band
  __shared__ __attribute__((aligned(16))) unsigned short BD_s[64][130];  // band-BD bf16

  const int it = blockIdx.x, bn = blockIdx.y;
  const int b = bn >> 4, hn = bn & 15;
  const int i0 = it * 64;
  const int tid = threadIdx.x, lane = tid & 63, w = tid >> 6;
  const int l15 = lane & 15, lg = lane >> 4;
  const int istrip = w * 16;

  // Q strips in registers: A-fragment for row istrip+l15, k-chunk kk*32+lg*8
  short8 qrw_r[2], qrr_r[2];
  {
    const size_t qrow = (((size_t)(b * 16 + hn)) * 1024 + i0 + istrip + l15) * 64 + lg * 8;
    qrw_r[0] = *(const short8*)&Qrw[qrow];
    qrw_r[1] = *(const short8*)&Qrw[qrow + 32];
    qrr_r[0] = *(const short8*)&Qrr[qrow];
    qrr_r[1] = *(const short8*)&Qrr[qrow + 32];
  }

  float m_st[4], l_st[4];
  f32x4 accO[4];
#pragma unroll
  for (int r = 0; r < 4; ++r) { m_st[r] = -1e30f; l_st[r] = 0.f; }
#pragma unroll
  for (int df = 0; df < 4; ++df) accO[df] = f4zero();

  const size_t kvbase = ((size_t)(b * 16 + hn)) * 2048 * 64;
  const int njt = it + 17;

  for (int jt = 0; jt < njt; ++jt) {
    const int j0 = jt * 64;
    __syncthreads();  // prev iter's PV reads done before restage
    // stage K tile + V transposed (swizzled)
#pragma unroll
    for (int u = 0; u < 2; ++u) {
      int c = tid + u * 256;
      int row = c >> 3, col = (c & 7) * 8;
      *(short8*)&KP_s[row][col] = *(const short8*)&Kd[kvbase + (size_t)(j0 + row) * 64 + col];
      short8 vv = *(const short8*)&Vd[kvbase + (size_t)(j0 + row) * 64 + col];
      const int grow = row >> 3, jo = row & 7;
#pragma unroll
      for (int e = 0; e < 8; ++e) {
        int d = col + e;
        Vt_s[d][((grow ^ (d >> 3)) << 3) + jo] = (unsigned short)vv[e];
      }
    }
    // stage RK band: rows jrb .. jrb+127
    const int jrb = j0 + 960 - i0;
#pragma unroll
    for (int u = 0; u < 4; ++u) {
      int c = tid + u * 256;
      int row = c >> 3, col = (c & 7) * 8;
      int jr = jrb + row;
      jr = jr < 0 ? 0 : (jr > 2047 ? 2047 : jr);
      *(short8*)&RK_s[row][col] = *(const short8*)&RKd[((size_t)hn * 2048 + jr) * 64 + col];
    }
    __syncthreads();  // staging visible

    // AC = Qrw . K^T  (wave strip 16 x 64)
    f32x4 accS[4];
#pragma unroll
    for (int ni = 0; ni < 4; ++ni) accS[ni] = f4zero();
#pragma unroll
    for (int kk = 0; kk < 2; ++kk) {
#pragma unroll
      for (int ni = 0; ni < 4; ++ni) {
        short8 bk = *(const short8*)&KP_s[ni * 16 + l15][kk * 32 + lg * 8];
        accS[ni] = mfma16(qrw_r[kk], bk, accS[ni]);
      }
    }
    // BD band: strip 16 x 128
    f32x4 accB[8];
#pragma unroll
    for (int fi = 0; fi < 8; ++fi) accB[fi] = f4zero();
#pragma unroll
    for (int kk = 0; kk < 2; ++kk) {
#pragma unroll
      for (int fi = 0; fi < 8; ++fi) {
        short8 br = *(const short8*)&RK_s[fi * 16 + l15][kk * 32 + lg * 8];
        accB[fi] = mfma16(qrr_r[kk], br, accB[fi]);
      }
    }
#pragma unroll
    for (int fi = 0; fi < 8; ++fi)
#pragma unroll
      for (int r = 0; r < 4; ++r)
        BD_s[istrip + lg * 4 + r][fi * 16 + l15] = f2bf(accB[fi][r]);
    __syncthreads();  // AC reads of K done -> P may overwrite KP_s

    // S = scale*(AC + BD[tj-ti+63]); mask; online softmax
    float p[4][4], mx[4];
#pragma unroll
    for (int r = 0; r < 4; ++r) mx[r] = -1e30f;
#pragma unroll
    for (int ni = 0; ni < 4; ++ni) {
      const int tj = ni * 16 + l15;
      const int gj = j0 + tj;
#pragma unroll
      for (int r = 0; r < 4; ++r) {
        const int ti = istrip + lg * 4 + r;
        const int gi = i0 + ti;
        float s = accS[ni][r] + bf2f(BD_s[ti][tj - ti + 63]);
        s = (gj <= gi + 1024) ? s * 0.125f : -1e30f;
        p[ni][r] = s;
        mx[r] = fmaxf(mx[r], s);
      }
    }
#pragma unroll
    for (int off = 1; off < 16; off <<= 1)
#pragma unroll
      for (int r = 0; r < 4; ++r) mx[r] = fmaxf(mx[r], __shfl_xor(mx[r], off));
    float rs[4], rowsum[4];
#pragma unroll
    for (int r = 0; r < 4; ++r) {
      float mnew = fmaxf(m_st[r], mx[r]);
      rs[r] = __expf(m_st[r] - mnew);
      m_st[r] = mnew;
      rowsum[r] = 0.f;
    }
#pragma unroll
    for (int ni = 0; ni < 4; ++ni)
#pragma unroll
      for (int r = 0; r < 4; ++r) {
        float e = __expf(p[ni][r] - m_st[r]);
        p[ni][r] = e;
        rowsum[r] += e;
      }
#pragma unroll
    for (int off = 1; off < 16; off <<= 1)
#pragma unroll
      for (int r = 0; r < 4; ++r) rowsum[r] += __shfl_xor(rowsum[r], off);
#pragma unroll
    for (int r = 0; r < 4; ++r) l_st[r] = l_st[r] * rs[r] + rowsum[r];
#pragma unroll
    for (int df = 0; df < 4; ++df) {
      f32x4 t = accO[df];
#pragma unroll
      for (int r = 0; r < 4; ++r) t[r] *= rs[r];
      accO[df] = t;
    }
    // write P (own strip rows; aliases K tile)
#pragma unroll
    for (int ni = 0; ni < 4; ++ni)
#pragma unroll
      for (int r = 0; r < 4; ++r)
        KP_s[istrip + lg * 4 + r][ni * 16 + l15] = f2bf(p[ni][r]);
    // PV: accO += P @ V   (B-fragment via swizzled Vt_s)
#pragma unroll
    for (int kk = 0; kk < 2; ++kk) {
      short8 ap = *(const short8*)&KP_s[istrip + l15][kk * 32 + lg * 8];
#pragma unroll
      for (int df = 0; df < 4; ++df) {
        const int dr = df * 16 + l15;
        short8 bv = *(const short8*)&Vt_s[dr][((kk * 4 + lg) ^ ((dr >> 3) & 7)) << 3];
        accO[df] = mfma16(ap, bv, accO[df]);
      }
    }
  }
  // epilogue
#pragma unroll
  for (int df = 0; df < 4; ++df)
#pragma unroll
    for (int r = 0; r < 4; ++r) {
      int ti = istrip + lg * 4 + r;
      int gi = i0 + ti;
      int d = df * 16 + l15;
      float v = accO[df][r] / l_st[r];
      AV[((size_t)gi * 2 + b) * 1024 + hn * 64 + d] = f2bf(v);
    }
}

// ---------------- residual + LayerNorm ----------------
__global__ __launch_bounds__(256) void k_ln(const float* __restrict__ wres,
                                            const float* __restrict__ ao,
                                            const float* __restrict__ g,
                                            const float* __restrict__ bb,
                                            float* __restrict__ out) {
  const int row = blockIdx.x;
  const int t4 = threadIdx.x * 4;
  const float4 xv = *(const float4*)(wres + (size_t)row * 1024 + t4);
  const float4 av = *(const float4*)(ao + (size_t)row * 1024 + t4);
  float x0 = xv.x + av.x, x1 = xv.y + av.y, x2 = xv.z + av.z, x3 = xv.w + av.w;
  float s1 = x0 + x1 + x2 + x3;
  float s2 = x0 * x0 + x1 * x1 + x2 * x2 + x3 * x3;
#pragma unroll
  for (int off = 1; off < 64; off <<= 1) {
    s1 += __shfl_xor(s1, off);
    s2 += __shfl_xor(s2, off);
  }
  __shared__ float red[2][4];
  const int wv = threadIdx.x >> 6;
  if ((threadIdx.x & 63) == 0) { red[0][wv] = s1; red[1][wv] = s2; }
  __syncthreads();
  s1 = red[0][0] + red[0][1] + red[0][2] + red[0][3];
  s2 = red[1][0] + red[1][1] + red[1][2] + red[1][3];
  const float mu = s1 * (1.f / 1024.f);
  const float var = s2 * (1.f / 1024.f) - mu * mu;
  const float inv = rsqrtf(var + 1e-5f);
  const float4 gv = *(const float4*)(g + t4);
  const float4 bv = *(const float4*)(bb + t4);
  float4 ov;
  ov.x = (x0 - mu) * inv * gv.x + bv.x;
  ov.y = (x1 - mu) * inv * gv.y + bv.y;
  ov.z = (x2 - mu) * inv * gv.z + bv.z;
  ov.w = (x3 - mu) * inv * gv.w + bv.w;
  *(float4*)(out + (size_t)row * 1024 + t4) = ov;
}

extern "C" void kernel_launch(void* const* d_in, const int* in_sizes, int n_in,
                              void* d_out, int out_size, void* d_ws, size_t ws_size,
                              hipStream_t stream) {
  const float* w     = (const float*)d_in[0];
  const float* r     = (const float*)d_in[1];
  const float* rwb   = (const float*)d_in[2];
  const float* rrb   = (const float*)d_in[3];
  const float* mems  = (const float*)d_in[4];
  const float* qkv_W = (const float*)d_in[6];
  const float* r_W   = (const float*)d_in[7];
  const float* o_W   = (const float*)d_in[8];
  const float* ln_g  = (const float*)d_in[9];
  const float* ln_b  = (const float*)d_in[10];
  float* out = (float*)d_out;
  char* ws = (char*)d_ws;

  unsigned short* A_cat = (unsigned short*)(ws + 0);          //  8 MB: [4096][1024]
  unsigned short* Wqkv  = (unsigned short*)(ws + 8388608);    //  6 MB: [3072][1024]
  unsigned short* rb    = (unsigned short*)(ws + 14680064);   //  4 MB: [2048][1024]
  unsigned short* Wr    = (unsigned short*)(ws + 18874368);   //  2 MB
  unsigned short* oWb   = (unsigned short*)(ws + 20971520);   //  2 MB
  unsigned short* Qrw   = (unsigned short*)(ws + 23068672);   //  4 MB: [b][n][1024][64]
  unsigned short* Qrr   = (unsigned short*)(ws + 27262976);   //  4 MB
  unsigned short* Kd    = (unsigned short*)(ws + 31457280);   //  8 MB: [b][n][2048][64]
  unsigned short* Vd    = (unsigned short*)(ws + 39845888);   //  8 MB
  unsigned short* RKd   = (unsigned short*)(ws + 48234496);   //  4 MB: [n][2048][64]
  unsigned short* AV    = (unsigned short*)(ws + 52428800);   //  4 MB: [2048][1024]
  float*          AO    = (float*)(ws + 56623104);            //  8 MB: [2048][1024]

  // fused converts: 11264 blocks cover all 6 regions
  k_conv_all<<<11264, 256, 0, stream>>>(mems, w, qkv_W, r, r_W, o_W,
                                        A_cat, A_cat + 2048 * 1024, Wqkv, rb, Wr, oWb);

  k_gemm_qkv<<<dim3(24, 32), 256, 0, stream>>>(A_cat, Wqkv, Qrw, Qrr, Kd, Vd, rwb, rrb);
  k_gemm_rk<<<dim3(8, 16), 256, 0, stream>>>(rb, Wr, RKd);
  k_attn<<<dim3(16, 32), 256, 0, stream>>>(Qrw, Qrr, Kd, Vd, RKd, AV);
  k_gemm_o<<<dim3(8, 16), 256, 0, stream>>>(AV, oWb, AO);
  k_ln<<<2048, 256, 0, stream>>>(w, AO, ln_g, ln_b, out);
}